// Round 3
// baseline (61.105 us; speedup 1.0000x reference)
//
#include <hip/hip_runtime.h>
#include <hip/hip_bf16.h>

// Chamfer distance, B=4, N=M=8192, fp32.
// d(x,y) = |x|^2 - 2 x.y + |y|^2  (the reference's own expansion).
// Per row we min over d' = |y|^2 - 2 x.y (constant |x|^2 shift preserves argmin),
// add |x|^2 back at the end, clamp >= 0, sqrt, mean.
// Inner loop uses packed fp32: v_pk_fma_f32 (2 pairs per instr) + v_min3_f32.

typedef float f32x2 __attribute__((ext_vector_type(2)));
typedef float f32x4 __attribute__((ext_vector_type(4)));

constexpr int TPB    = 256;
constexpr int XPT    = 8;     // rows per thread -> 2048 rows/block
constexpr int CHUNK  = 256;   // y-points per block
constexpr int YSPLIT = 32;    // 8192 / 256
constexpr int NPTS   = 8192;
constexpr int BATCH  = 4;
constexpr int NROWS  = 2 * BATCH * NPTS;   // 65536

__device__ __forceinline__ f32x2 pk_fma(f32x2 a, f32x2 b, f32x2 c) {
    f32x2 d;
    asm("v_pk_fma_f32 %0, %1, %2, %3" : "=v"(d) : "v"(a), "v"(b), "v"(c));
    return d;
}

template<bool USE_TABLE>
__global__ __launch_bounds__(TPB, 4)
void chamfer_partial(const float* __restrict__ P1, const float* __restrict__ P2,
                     float* __restrict__ table, unsigned* __restrict__ amin) {
    const int b    = blockIdx.y;
    const int dir  = blockIdx.z & 1;
    const int yseg = blockIdx.z >> 1;

    const float* X = (dir ? P2 : P1) + (size_t)b * NPTS * 3;
    const float* Y = (dir ? P1 : P2) + (size_t)b * NPTS * 3 + (size_t)yseg * CHUNK * 3;

    __shared__ f32x4 ys0[CHUNK / 4], ys1[CHUNK / 4], ys2[CHUNK / 4], ys3[CHUNK / 4];
    const int tid = threadIdx.x;

    // stage CHUNK y-points, AoS -> SoA, plus |y|^2  (CHUNK == TPB: one point/thread)
    {
        float a = Y[3 * tid + 0], bb = Y[3 * tid + 1], c = Y[3 * tid + 2];
        ((float*)ys0)[tid] = a;
        ((float*)ys1)[tid] = bb;
        ((float*)ys2)[tid] = c;
        ((float*)ys3)[tid] = fmaf(a, a, fmaf(bb, bb, c * c));
    }

    const int rowbase = blockIdx.x * (TPB * XPT);
    f32x2 nx0[XPT], nx1[XPT], nx2[XPT];
    float x2s[XPT], md[XPT];
    #pragma unroll
    for (int k = 0; k < XPT; ++k) {
        int r = rowbase + k * TPB + tid;
        float a = X[3 * r + 0], bb = X[3 * r + 1], c = X[3 * r + 2];
        float na = -2.f * a, nb = -2.f * bb, nc = -2.f * c;
        nx0[k] = {na, na};
        nx1[k] = {nb, nb};
        nx2[k] = {nc, nc};
        x2s[k] = fmaf(a, a, fmaf(bb, bb, c * c));
        md[k]  = 1e30f;
    }
    __syncthreads();

    #pragma unroll 2
    for (int j = 0; j < CHUNK / 4; ++j) {
        // uniform-address ds_read_b128: broadcast, conflict-free
        f32x4 q0 = ys0[j], q1 = ys1[j], q2 = ys2[j], qs = ys3[j];
        f32x2 y0l = q0.lo, y0h = q0.hi;
        f32x2 y1l = q1.lo, y1h = q1.hi;
        f32x2 y2l = q2.lo, y2h = q2.hi;
        f32x2 ysl = qs.lo, ysh = qs.hi;
        #pragma unroll
        for (int k = 0; k < XPT; ++k) {
            f32x2 a = pk_fma(nx0[k], y0l, ysl);   // d' = |y|^2 - 2 x.y
            a = pk_fma(nx1[k], y1l, a);
            a = pk_fma(nx2[k], y2l, a);
            f32x2 c2 = pk_fma(nx0[k], y0h, ysh);
            c2 = pk_fma(nx1[k], y1h, c2);
            c2 = pk_fma(nx2[k], y2h, c2);
            float t = fminf(fminf(md[k], a.x), a.y);    // v_min3_f32
            md[k]   = fminf(fminf(t, c2.x), c2.y);      // v_min3_f32
        }
    }

    const size_t rowoff = (size_t)(dir * BATCH + b) * NPTS + rowbase;
    #pragma unroll
    for (int k = 0; k < XPT; ++k) {
        float d = fmaxf(md[k] + x2s[k], 0.f);
        if (USE_TABLE)
            table[(size_t)yseg * NROWS + rowoff + k * TPB + tid] = d;
        else
            atomicMin(&amin[rowoff + k * TPB + tid], __float_as_uint(d));
    }
}

template<bool USE_TABLE>
__global__ __launch_bounds__(TPB)
void chamfer_reduce(const float* __restrict__ table, const unsigned* __restrict__ amin,
                    float* __restrict__ sum) {
    const int r = blockIdx.x * TPB + threadIdx.x;
    float m;
    if (USE_TABLE) {
        m = 1e30f;
        #pragma unroll 8
        for (int s = 0; s < YSPLIT; ++s)
            m = fminf(m, table[(size_t)s * NROWS + r]);   // coalesced across threads
    } else {
        m = __uint_as_float(amin[r]);
    }
    float v = sqrtf(fmaxf(m, 0.f));
    #pragma unroll
    for (int off = 32; off; off >>= 1) v += __shfl_down(v, off, 64);
    __shared__ float ws[TPB / 64];
    const int tid = threadIdx.x;
    if ((tid & 63) == 0) ws[tid >> 6] = v;
    __syncthreads();
    if (tid == 0) {
        float t = 0.f;
        #pragma unroll
        for (int w = 0; w < TPB / 64; ++w) t += ws[w];
        atomicAdd(sum, t);
    }
}

__global__ void chamfer_final(const float* __restrict__ sum, float* __restrict__ out) {
    out[0] = sum[0] * (1.0f / NROWS);   // (d1+d2)/2 with equal counts
}

extern "C" void kernel_launch(void* const* d_in, const int* in_sizes, int n_in,
                              void* d_out, int out_size, void* d_ws, size_t ws_size,
                              hipStream_t stream) {
    const float* p1 = (const float*)d_in[0];
    const float* p2 = (const float*)d_in[1];
    float* out = (float*)d_out;

    const size_t table_bytes = (size_t)NROWS * YSPLIT * sizeof(float);   // 8 MB
    const bool use_table = ws_size >= table_bytes + sizeof(float);

    dim3 gridA(NPTS / (TPB * XPT), BATCH, 2 * YSPLIT);   // (4,4,64) = 1024 blocks

    if (use_table) {
        float* table = (float*)d_ws;
        float* sum   = (float*)((char*)d_ws + table_bytes);
        hipMemsetAsync(sum, 0, sizeof(float), stream);
        chamfer_partial<true><<<gridA, TPB, 0, stream>>>(p1, p2, table, nullptr);
        chamfer_reduce<true><<<dim3(NROWS / TPB), TPB, 0, stream>>>(table, nullptr, sum);
        chamfer_final<<<1, 1, 0, stream>>>(sum, out);
    } else {
        unsigned* amin = (unsigned*)d_ws;
        float* sum = (float*)((char*)d_ws + (size_t)NROWS * sizeof(unsigned));
        hipMemsetAsync(amin, 0xFF, (size_t)NROWS * sizeof(unsigned), stream);
        hipMemsetAsync(sum, 0, sizeof(float), stream);
        chamfer_partial<false><<<gridA, TPB, 0, stream>>>(p1, p2, nullptr, amin);
        chamfer_reduce<false><<<dim3(NROWS / TPB), TPB, 0, stream>>>(nullptr, amin, sum);
        chamfer_final<<<1, 1, 0, stream>>>(sum, out);
    }
}

// Round 4
// 49.632 us; speedup vs baseline: 1.2312x; 1.2312x over previous
//
#include <hip/hip_runtime.h>
#include <hip/hip_bf16.h>

// Chamfer distance via MFMA (bf16 hi/lo split, "3-term Ootomo" precision).
// d(x,y) = |y|^2 - 2x.y + |x|^2 packed as a K=13 dot product in
// mfma_f32_32x32x16_bf16:  y on M-axis (A), x on N-axis (B), so the min over y
// is an in-lane reduce over the 16 accumulator regs + one shfl_xor(32).
//
// K slots:  0-2: yh * (-2xh)   3-5: yl * (-2xh)   6-8: yh * (-2xl)
//           9: |y|2_h * 1   10: |y|2_l * 1   11: 1 * |x|2_h   12: 1 * |x|2_l
//           13-15: zero
// Dropped term -2*xl.yl ~ 2^-16 relative (~1e-5 abs) -- negligible vs 2.5e-3.

typedef float f32x16 __attribute__((ext_vector_type(16)));
typedef short bf16x8 __attribute__((ext_vector_type(8)));

constexpr int NPTS    = 8192;
constexpr int BATCH   = 4;
constexpr int NPT_TOT = 2 * BATCH * NPTS;   // 65536 points across both clouds

__device__ __forceinline__ ushort bf16_rne(float v, float& back) {
    unsigned u = __float_as_uint(v);
    unsigned r = (u + 0x7FFFu + ((u >> 16) & 1u)) >> 16;
    back = __uint_as_float(r << 16);
    return (ushort)r;
}

union Frag { ushort u[8]; uint4 q; };

__global__ __launch_bounds__(256)
void chamfer_prep(const float* __restrict__ P1, const float* __restrict__ P2,
                  uint4* __restrict__ Atab, uint4* __restrict__ Btab) {
    const int p = blockIdx.x * 256 + threadIdx.x;          // 0..65535
    const int cloud = p >> 15;
    const float* src = (cloud ? P2 : P1) + (size_t)(p & (4 * NPTS - 1)) * 3;
    const float v0 = src[0], v1 = src[1], v2 = src[2];

    float h0f, h1f, h2f, d;
    const ushort h0 = bf16_rne(v0, h0f);
    const ushort h1 = bf16_rne(v1, h1f);
    const ushort h2 = bf16_rne(v2, h2f);
    const ushort l0 = bf16_rne(v0 - h0f, d);
    const ushort l1 = bf16_rne(v1 - h1f, d);
    const ushort l2 = bf16_rne(v2 - h2f, d);
    // -2*hi, -2*lo are exact rescales of bf16 values
    float n0f, n1f, n2f, m0f, m1f, m2f;
    const ushort n0 = bf16_rne(-2.f * h0f, n0f);
    const ushort n1 = bf16_rne(-2.f * h1f, n1f);
    const ushort n2 = bf16_rne(-2.f * h2f, n2f);
    float l0f, l1f, l2f;
    bf16_rne(v0 - h0f, l0f); bf16_rne(v1 - h1f, l1f); bf16_rne(v2 - h2f, l2f);
    const ushort m0 = bf16_rne(-2.f * l0f, m0f);
    const ushort m1 = bf16_rne(-2.f * l1f, m1f);
    const ushort m2 = bf16_rne(-2.f * l2f, m2f);
    // |p|^2 hi/lo split
    const float s = fmaf(v0, v0, fmaf(v1, v1, v2 * v2));
    float shf;
    const ushort sh = bf16_rne(s, shf);
    const ushort sl = bf16_rne(s - shf, d);
    const ushort ONE = 0x3F80;

    Frag A0; A0.u[0]=h0; A0.u[1]=h1; A0.u[2]=h2; A0.u[3]=l0; A0.u[4]=l1; A0.u[5]=l2; A0.u[6]=h0; A0.u[7]=h1;
    Frag A1; A1.u[0]=h2; A1.u[1]=sh; A1.u[2]=sl; A1.u[3]=ONE; A1.u[4]=ONE; A1.u[5]=0; A1.u[6]=0; A1.u[7]=0;
    Frag B0; B0.u[0]=n0; B0.u[1]=n1; B0.u[2]=n2; B0.u[3]=n0; B0.u[4]=n1; B0.u[5]=n2; B0.u[6]=m0; B0.u[7]=m1;
    Frag B1; B1.u[0]=m2; B1.u[1]=ONE; B1.u[2]=ONE; B1.u[3]=sh; B1.u[4]=sl; B1.u[5]=0; B1.u[6]=0; B1.u[7]=0;

    Atab[p]           = A0.q;
    Atab[NPT_TOT + p] = A1.q;
    Btab[p]           = B0.q;
    Btab[NPT_TOT + p] = B1.q;
}

template<int YSEG>
__global__ __launch_bounds__(256, 4)
void chamfer_mfma(const uint4* __restrict__ Atab, const uint4* __restrict__ Btab,
                  float* __restrict__ mintab) {
    const int lane = threadIdx.x & 63;
    const int w    = threadIdx.x >> 6;
    const int col  = lane & 31;
    const int g    = lane >> 5;          // k-group: 0 -> k0-7 table, 1 -> k8-15 table

    const int xblk = blockIdx.x;         // 0..7   (1024 x-points per block)
    const int comb = blockIdx.y;         // 0..7   dir*4+b
    const int yseg = blockIdx.z;         // 0..YSEG-1
    const int dir  = comb >> 2;
    const int b    = comb & 3;

    const int xbase = (dir * BATCH + b) * NPTS + xblk * 1024 + w * 256;
    const int ybase = ((1 - dir) * BATCH + b) * NPTS + yseg * (NPTS / YSEG);

    const bf16x8* At = (const bf16x8*)Atab;
    const bf16x8* Bt = (const bf16x8*)Btab;

    // 8 B-fragments (x side), each 32 x-points, held in registers
    bf16x8 Bf[8];
    #pragma unroll
    for (int t = 0; t < 8; ++t)
        Bf[t] = Bt[g * NPT_TOT + xbase + t * 32 + col];

    const f32x16 zero = {};
    float md[8];
    #pragma unroll
    for (int t = 0; t < 8; ++t) md[t] = 1e30f;

    constexpr int YI = (NPTS / YSEG) / 32;
    #pragma unroll 2
    for (int yi = 0; yi < YI; ++yi) {
        const bf16x8 Af = At[g * NPT_TOT + ybase + yi * 32 + col];
        #pragma unroll
        for (int t = 0; t < 8; ++t) {
            f32x16 D = __builtin_amdgcn_mfma_f32_32x32x16_bf16(Af, Bf[t], zero, 0, 0, 0);
            float m0 = fminf(fminf(D[0],  D[1]),  fminf(D[2],  D[3]));
            float m1 = fminf(fminf(D[4],  D[5]),  fminf(D[6],  D[7]));
            float m2 = fminf(fminf(D[8],  D[9]),  fminf(D[10], D[11]));
            float m3 = fminf(fminf(D[12], D[13]), fminf(D[14], D[15]));
            md[t] = fminf(md[t], fminf(fminf(m0, m1), fminf(m2, m3)));
        }
    }

    // fold the two half-waves (rows 4g..): both halves then hold min over all 32 rows
    #pragma unroll
    for (int t = 0; t < 8; ++t)
        md[t] = fminf(md[t], __shfl_xor(md[t], 32, 64));

    if (g == 0) {
        #pragma unroll
        for (int t = 0; t < 8; ++t)
            mintab[(size_t)yseg * NPT_TOT + xbase + t * 32 + col] = md[t];
    }
}

template<int YSEG>
__global__ __launch_bounds__(256)
void chamfer_reduce(const float* __restrict__ mintab, float* __restrict__ sum) {
    const int r = blockIdx.x * 256 + threadIdx.x;
    float m = 1e30f;
    #pragma unroll
    for (int s = 0; s < YSEG; ++s)
        m = fminf(m, mintab[(size_t)s * NPT_TOT + r]);
    float v = sqrtf(fmaxf(m, 0.f));
    #pragma unroll
    for (int off = 32; off; off >>= 1) v += __shfl_down(v, off, 64);
    __shared__ float ws[4];
    const int tid = threadIdx.x;
    if ((tid & 63) == 0) ws[tid >> 6] = v;
    __syncthreads();
    if (tid == 0) {
        float t = ws[0] + ws[1] + ws[2] + ws[3];
        atomicAdd(sum, t);
    }
}

__global__ void chamfer_final(const float* __restrict__ sum, float* __restrict__ out) {
    out[0] = sum[0] * (1.0f / NPT_TOT);
}

extern "C" void kernel_launch(void* const* d_in, const int* in_sizes, int n_in,
                              void* d_out, int out_size, void* d_ws, size_t ws_size,
                              hipStream_t stream) {
    const float* p1 = (const float*)d_in[0];
    const float* p2 = (const float*)d_in[1];
    float* out = (float*)d_out;

    const size_t tab_bytes = (size_t)2 * NPT_TOT * 16;          // 2 MB each
    uint4* Atab = (uint4*)d_ws;
    uint4* Btab = (uint4*)((char*)d_ws + tab_bytes);
    float* mintab = (float*)((char*)d_ws + 2 * tab_bytes);      // after 4 MB

    const size_t need16 = 2 * tab_bytes + (size_t)16 * NPT_TOT * 4 + 4;  // 8 MB + 4
    const bool use16 = ws_size >= need16;
    const int YSEG = use16 ? 16 : 8;
    float* sum = (float*)((char*)d_ws + 2 * tab_bytes + (size_t)YSEG * NPT_TOT * 4);

    hipMemsetAsync(sum, 0, sizeof(float), stream);
    chamfer_prep<<<dim3(NPT_TOT / 256), 256, 0, stream>>>(p1, p2, Atab, Btab);

    if (use16) {
        chamfer_mfma<16><<<dim3(8, 8, 16), 256, 0, stream>>>(Atab, Btab, mintab);
        chamfer_reduce<16><<<dim3(NPT_TOT / 256), 256, 0, stream>>>(mintab, sum);
    } else {
        chamfer_mfma<8><<<dim3(8, 8, 8), 256, 0, stream>>>(Atab, Btab, mintab);
        chamfer_reduce<8><<<dim3(NPT_TOT / 256), 256, 0, stream>>>(mintab, sum);
    }
    chamfer_final<<<1, 1, 0, stream>>>(sum, out);
}

// Round 7
// 49.294 us; speedup vs baseline: 1.2396x; 1.0069x over previous
//
#include <hip/hip_runtime.h>
#include <hip/hip_bf16.h>

// Chamfer distance via MFMA (bf16 hi/lo split, 3-term Ootomo precision).
// d(x,y) = |y|^2 - 2x.y + |x|^2 packed as a K=13 dot product in
// mfma_f32_32x32x16_bf16. y on M-axis (A), x on N-axis (B): the min over y is
// an in-lane reduce over the 16 accumulator regs + shfl_xor(32).
//
// K slots: 0-2: yh*(-2xh)  3-5: yl*(-2xh)  6-8: yh*(-2xl)
//          9: |y|2h*1  10: |y|2l*1  11: 1*|x|2h  12: 1*|x|2l   13-15: 0
//
// BISECT ROUND: this is the round-4 PASSING code verbatim (memset-init sum,
// fminf-tree reduce, no inline asm, no pipeline, separate final kernel).
// Single delta: __launch_bounds__(256,4) -> (256,2) on chamfer_mfma to lift
// the 128-VGPR cap (8 live f32x16 accumulators need ~200 VGPR -> spills).

typedef float f32x16 __attribute__((ext_vector_type(16)));
typedef short bf16x8 __attribute__((ext_vector_type(8)));

constexpr int NPTS    = 8192;
constexpr int BATCH   = 4;
constexpr int NPT_TOT = 2 * BATCH * NPTS;   // 65536

__device__ __forceinline__ ushort bf16_rne(float v, float& back) {
    unsigned u = __float_as_uint(v);
    unsigned r = (u + 0x7FFFu + ((u >> 16) & 1u)) >> 16;
    back = __uint_as_float(r << 16);
    return (ushort)r;
}

union Frag { ushort u[8]; uint4 q; };

__global__ __launch_bounds__(256)
void chamfer_prep(const float* __restrict__ P1, const float* __restrict__ P2,
                  uint4* __restrict__ Atab, uint4* __restrict__ Btab) {
    const int p = blockIdx.x * 256 + threadIdx.x;          // 0..65535
    const int cloud = p >> 15;
    const float* src = (cloud ? P2 : P1) + (size_t)(p & (BATCH * NPTS - 1)) * 3;
    const float v0 = src[0], v1 = src[1], v2 = src[2];

    float h0f, h1f, h2f, d;
    const ushort h0 = bf16_rne(v0, h0f);
    const ushort h1 = bf16_rne(v1, h1f);
    const ushort h2 = bf16_rne(v2, h2f);
    const ushort l0 = bf16_rne(v0 - h0f, d);
    const ushort l1 = bf16_rne(v1 - h1f, d);
    const ushort l2 = bf16_rne(v2 - h2f, d);
    // -2*hi, -2*lo are exact rescales of bf16 values
    float n0f, n1f, n2f, m0f, m1f, m2f;
    const ushort n0 = bf16_rne(-2.f * h0f, n0f);
    const ushort n1 = bf16_rne(-2.f * h1f, n1f);
    const ushort n2 = bf16_rne(-2.f * h2f, n2f);
    float l0f, l1f, l2f;
    bf16_rne(v0 - h0f, l0f); bf16_rne(v1 - h1f, l1f); bf16_rne(v2 - h2f, l2f);
    const ushort m0 = bf16_rne(-2.f * l0f, m0f);
    const ushort m1 = bf16_rne(-2.f * l1f, m1f);
    const ushort m2 = bf16_rne(-2.f * l2f, m2f);
    // |p|^2 hi/lo split
    const float s = fmaf(v0, v0, fmaf(v1, v1, v2 * v2));
    float shf;
    const ushort sh = bf16_rne(s, shf);
    const ushort sl = bf16_rne(s - shf, d);
    const ushort ONE = 0x3F80;

    Frag A0; A0.u[0]=h0; A0.u[1]=h1; A0.u[2]=h2; A0.u[3]=l0; A0.u[4]=l1; A0.u[5]=l2; A0.u[6]=h0; A0.u[7]=h1;
    Frag A1; A1.u[0]=h2; A1.u[1]=sh; A1.u[2]=sl; A1.u[3]=ONE; A1.u[4]=ONE; A1.u[5]=0; A1.u[6]=0; A1.u[7]=0;
    Frag B0; B0.u[0]=n0; B0.u[1]=n1; B0.u[2]=n2; B0.u[3]=n0; B0.u[4]=n1; B0.u[5]=n2; B0.u[6]=m0; B0.u[7]=m1;
    Frag B1; B1.u[0]=m2; B1.u[1]=ONE; B1.u[2]=ONE; B1.u[3]=sh; B1.u[4]=sl; B1.u[5]=0; B1.u[6]=0; B1.u[7]=0;

    Atab[p]           = A0.q;
    Atab[NPT_TOT + p] = A1.q;
    Btab[p]           = B0.q;
    Btab[NPT_TOT + p] = B1.q;
}

template<int YSEG>
__global__ __launch_bounds__(256, 2)
void chamfer_mfma(const uint4* __restrict__ Atab, const uint4* __restrict__ Btab,
                  float* __restrict__ mintab) {
    const int lane = threadIdx.x & 63;
    const int w    = threadIdx.x >> 6;
    const int col  = lane & 31;
    const int g    = lane >> 5;          // k-group: 0 -> k0-7 table, 1 -> k8-15 table

    const int xblk = blockIdx.x;         // 0..7   (1024 x-points per block)
    const int comb = blockIdx.y;         // 0..7   dir*4+b
    const int yseg = blockIdx.z;         // 0..YSEG-1
    const int dir  = comb >> 2;
    const int b    = comb & 3;

    const int xbase = (dir * BATCH + b) * NPTS + xblk * 1024 + w * 256;
    const int ybase = ((1 - dir) * BATCH + b) * NPTS + yseg * (NPTS / YSEG);

    const bf16x8* At = (const bf16x8*)Atab;
    const bf16x8* Bt = (const bf16x8*)Btab;

    // 8 B-fragments (x side), each 32 x-points, held in registers
    bf16x8 Bf[8];
    #pragma unroll
    for (int t = 0; t < 8; ++t)
        Bf[t] = Bt[g * NPT_TOT + xbase + t * 32 + col];

    const f32x16 zero = {};
    float md[8];
    #pragma unroll
    for (int t = 0; t < 8; ++t) md[t] = 1e30f;

    constexpr int YI = (NPTS / YSEG) / 32;
    #pragma unroll 2
    for (int yi = 0; yi < YI; ++yi) {
        const bf16x8 Af = At[g * NPT_TOT + ybase + yi * 32 + col];
        #pragma unroll
        for (int t = 0; t < 8; ++t) {
            f32x16 D = __builtin_amdgcn_mfma_f32_32x32x16_bf16(Af, Bf[t], zero, 0, 0, 0);
            float m0 = fminf(fminf(D[0],  D[1]),  fminf(D[2],  D[3]));
            float m1 = fminf(fminf(D[4],  D[5]),  fminf(D[6],  D[7]));
            float m2 = fminf(fminf(D[8],  D[9]),  fminf(D[10], D[11]));
            float m3 = fminf(fminf(D[12], D[13]), fminf(D[14], D[15]));
            md[t] = fminf(md[t], fminf(fminf(m0, m1), fminf(m2, m3)));
        }
    }

    // fold the two half-waves (rows 4g..): both halves then hold min over all 32 rows
    #pragma unroll
    for (int t = 0; t < 8; ++t)
        md[t] = fminf(md[t], __shfl_xor(md[t], 32, 64));

    if (g == 0) {
        #pragma unroll
        for (int t = 0; t < 8; ++t)
            mintab[(size_t)yseg * NPT_TOT + xbase + t * 32 + col] = md[t];
    }
}

template<int YSEG>
__global__ __launch_bounds__(256)
void chamfer_reduce(const float* __restrict__ mintab, float* __restrict__ sum) {
    const int r = blockIdx.x * 256 + threadIdx.x;
    float m = 1e30f;
    #pragma unroll
    for (int s = 0; s < YSEG; ++s)
        m = fminf(m, mintab[(size_t)s * NPT_TOT + r]);
    float v = sqrtf(fmaxf(m, 0.f));
    #pragma unroll
    for (int off = 32; off; off >>= 1) v += __shfl_down(v, off, 64);
    __shared__ float ws[4];
    const int tid = threadIdx.x;
    if ((tid & 63) == 0) ws[tid >> 6] = v;
    __syncthreads();
    if (tid == 0) {
        float t = ws[0] + ws[1] + ws[2] + ws[3];
        atomicAdd(sum, t);
    }
}

__global__ void chamfer_final(const float* __restrict__ sum, float* __restrict__ out) {
    out[0] = sum[0] * (1.0f / NPT_TOT);
}

extern "C" void kernel_launch(void* const* d_in, const int* in_sizes, int n_in,
                              void* d_out, int out_size, void* d_ws, size_t ws_size,
                              hipStream_t stream) {
    const float* p1 = (const float*)d_in[0];
    const float* p2 = (const float*)d_in[1];
    float* out = (float*)d_out;

    const size_t tab_bytes = (size_t)2 * NPT_TOT * 16;          // 2 MB each
    uint4* Atab = (uint4*)d_ws;
    uint4* Btab = (uint4*)((char*)d_ws + tab_bytes);
    float* mintab = (float*)((char*)d_ws + 2 * tab_bytes);      // after 4 MB

    const size_t need16 = 2 * tab_bytes + (size_t)16 * NPT_TOT * 4 + 4;  // 8 MB + 4
    const bool use16 = ws_size >= need16;
    const int YSEG = use16 ? 16 : 8;
    float* sum = (float*)((char*)d_ws + 2 * tab_bytes + (size_t)YSEG * NPT_TOT * 4);

    hipMemsetAsync(sum, 0, sizeof(float), stream);
    chamfer_prep<<<dim3(NPT_TOT / 256), 256, 0, stream>>>(p1, p2, Atab, Btab);

    if (use16) {
        chamfer_mfma<16><<<dim3(8, 8, 16), 256, 0, stream>>>(Atab, Btab, mintab);
        chamfer_reduce<16><<<dim3(NPT_TOT / 256), 256, 0, stream>>>(mintab, sum);
    } else {
        chamfer_mfma<8><<<dim3(8, 8, 8), 256, 0, stream>>>(Atab, Btab, mintab);
        chamfer_reduce<8><<<dim3(NPT_TOT / 256), 256, 0, stream>>>(mintab, sum);
    }
    chamfer_final<<<1, 1, 0, stream>>>(sum, out);
}

// Round 8
// 38.463 us; speedup vs baseline: 1.5887x; 1.2816x over previous
//
#include <hip/hip_runtime.h>
#include <hip/hip_bf16.h>

// Chamfer distance via MFMA (bf16 hi/lo split, 3-term Ootomo precision).
// d(x,y) = |y|^2 - 2x.y + |x|^2 packed as a K=13 dot product in
// mfma_f32_32x32x16_bf16. One MFMA computes full K=16 for a 32y x 32x tile
// (lanes<32 carry k=0..7 slots, lanes>=32 carry k=8..15). Min over y is the
// in-lane 16-reg fminf tree + shfl_xor(32) fold. Verified round 4/7 (absmax 0).
//
// Round-8 structure: prep fused into the MFMA kernel (A-frags built in LDS,
// B-frags in registers), no-init reduce (per-block partials) + 1-block final.
// 3 graph nodes, no memset, no atomics, no cross-block publish.
// Lesson r5/6: never feed MFMA results into inline asm (hazard); fminf only.

typedef float f32x16 __attribute__((ext_vector_type(16)));
typedef short bf16x8 __attribute__((ext_vector_type(8)));

constexpr int NPTS    = 8192;
constexpr int BATCH   = 4;
constexpr int NPT_TOT = 2 * BATCH * NPTS;   // 65536 rows total
constexpr int YSEG    = 16;
constexpr int SEG     = NPTS / YSEG;        // 512 y-points per block
constexpr int NRED    = 256;                // reduce blocks

__device__ __forceinline__ ushort bf16_rne(float v, float& back) {
    unsigned u = __float_as_uint(v);
    unsigned r = (u + 0x7FFFu + ((u >> 16) & 1u)) >> 16;
    back = __uint_as_float(r << 16);
    return (ushort)r;
}

union FragU { ushort u[8]; uint4 q; bf16x8 v; };

__global__ __launch_bounds__(256, 2)
void chamfer_fused(const float* __restrict__ P1, const float* __restrict__ P2,
                   float* __restrict__ mintab) {
    const int tid  = threadIdx.x;
    const int lane = tid & 63;
    const int w    = tid >> 6;
    const int col  = lane & 31;
    const int g    = lane >> 5;          // k-half: 0 -> slots 0-7, 1 -> slots 8-15

    const int xblk = blockIdx.x;         // 0..7   (1024 x-points per block)
    const int comb = blockIdx.y;         // 0..7   dir*4+b
    const int yseg = blockIdx.z;         // 0..15
    const int dir  = comb >> 2;
    const int b    = comb & 3;

    const float* Xb = (dir ? P2 : P1) + (size_t)b * NPTS * 3;
    const float* Yb = (dir ? P1 : P2) + (size_t)b * NPTS * 3 + (size_t)yseg * SEG * 3;

    __shared__ uint4 lds_a[2 * SEG];     // 16 KB: [half][yp] A-role fragments

    // ---- build A-role frags for this block's 512 y-points (2 pts/thread) ----
    for (int yp = tid; yp < SEG; yp += 256) {
        const float v0 = Yb[yp * 3 + 0], v1 = Yb[yp * 3 + 1], v2 = Yb[yp * 3 + 2];
        float h0f, h1f, h2f, d;
        const ushort h0 = bf16_rne(v0, h0f);
        const ushort h1 = bf16_rne(v1, h1f);
        const ushort h2 = bf16_rne(v2, h2f);
        const ushort l0 = bf16_rne(v0 - h0f, d);
        const ushort l1 = bf16_rne(v1 - h1f, d);
        const ushort l2 = bf16_rne(v2 - h2f, d);
        const float  s  = fmaf(v0, v0, fmaf(v1, v1, v2 * v2));
        float shf;
        const ushort sh = bf16_rne(s, shf);
        const ushort sl = bf16_rne(s - shf, d);
        const ushort ONE = 0x3F80;
        FragU A0, A1;
        A0.u[0]=h0; A0.u[1]=h1; A0.u[2]=h2; A0.u[3]=l0; A0.u[4]=l1; A0.u[5]=l2; A0.u[6]=h0; A0.u[7]=h1;
        A1.u[0]=h2; A1.u[1]=sh; A1.u[2]=sl; A1.u[3]=ONE; A1.u[4]=ONE; A1.u[5]=0; A1.u[6]=0; A1.u[7]=0;
        lds_a[yp]       = A0.q;
        lds_a[SEG + yp] = A1.q;
    }

    // ---- build B-role frags in registers (this wave's 256 x-points) ----
    const int xloc = xblk * 1024 + w * 256;
    bf16x8 Bf[8];
    #pragma unroll
    for (int t = 0; t < 8; ++t) {
        const int xp = xloc + t * 32 + col;
        const float v0 = Xb[xp * 3 + 0], v1 = Xb[xp * 3 + 1], v2 = Xb[xp * 3 + 2];
        float h0f, h1f, h2f, dd;
        bf16_rne(v0, h0f); bf16_rne(v1, h1f); bf16_rne(v2, h2f);
        float l0f, l1f, l2f;
        bf16_rne(v0 - h0f, l0f); bf16_rne(v1 - h1f, l1f); bf16_rne(v2 - h2f, l2f);
        const ushort n0 = bf16_rne(-2.f * h0f, dd);
        const ushort n1 = bf16_rne(-2.f * h1f, dd);
        const ushort n2 = bf16_rne(-2.f * h2f, dd);
        const ushort m0 = bf16_rne(-2.f * l0f, dd);
        const ushort m1 = bf16_rne(-2.f * l1f, dd);
        const ushort m2 = bf16_rne(-2.f * l2f, dd);
        const float  s  = fmaf(v0, v0, fmaf(v1, v1, v2 * v2));
        float shf;
        const ushort sh = bf16_rne(s, shf);
        const ushort sl = bf16_rne(s - shf, dd);
        const ushort ONE = 0x3F80;
        FragU B;
        B.u[0] = g ? m2  : n0;
        B.u[1] = g ? ONE : n1;
        B.u[2] = g ? ONE : n2;
        B.u[3] = g ? sh  : n0;
        B.u[4] = g ? sl  : n1;
        B.u[5] = g ? 0   : n2;
        B.u[6] = g ? 0   : m0;
        B.u[7] = g ? 0   : m1;
        Bf[t] = B.v;
    }
    __syncthreads();

    // ---- main loop: verbatim round-7 math, A-frags now from LDS ----
    const f32x16 zero = {};
    float md[8];
    #pragma unroll
    for (int t = 0; t < 8; ++t) md[t] = 1e30f;

    #pragma unroll 2
    for (int yi = 0; yi < SEG / 32; ++yi) {
        FragU AfU;
        AfU.q = lds_a[g * SEG + yi * 32 + col];
        const bf16x8 Af = AfU.v;
        #pragma unroll
        for (int t = 0; t < 8; ++t) {
            f32x16 D = __builtin_amdgcn_mfma_f32_32x32x16_bf16(Af, Bf[t], zero, 0, 0, 0);
            float m0 = fminf(fminf(D[0],  D[1]),  fminf(D[2],  D[3]));
            float m1 = fminf(fminf(D[4],  D[5]),  fminf(D[6],  D[7]));
            float m2 = fminf(fminf(D[8],  D[9]),  fminf(D[10], D[11]));
            float m3 = fminf(fminf(D[12], D[13]), fminf(D[14], D[15]));
            md[t] = fminf(md[t], fminf(fminf(m0, m1), fminf(m2, m3)));
        }
    }

    #pragma unroll
    for (int t = 0; t < 8; ++t)
        md[t] = fminf(md[t], __shfl_xor(md[t], 32, 64));

    if (g == 0) {
        const size_t rowbase = (size_t)yseg * NPT_TOT
                             + (size_t)(dir * BATCH + b) * NPTS + xloc;
        #pragma unroll
        for (int t = 0; t < 8; ++t)
            mintab[rowbase + t * 32 + col] = md[t];
    }
}

__global__ __launch_bounds__(256)
void chamfer_reduce(const float* __restrict__ mintab, float* __restrict__ partials) {
    const int r = blockIdx.x * 256 + threadIdx.x;
    float m = mintab[r];
    #pragma unroll
    for (int s = 1; s < YSEG; ++s)
        m = fminf(m, mintab[(size_t)s * NPT_TOT + r]);
    float v = sqrtf(fmaxf(m, 0.f));
    #pragma unroll
    for (int off = 32; off; off >>= 1) v += __shfl_down(v, off, 64);
    __shared__ float ws[4];
    const int tid = threadIdx.x;
    if ((tid & 63) == 0) ws[tid >> 6] = v;
    __syncthreads();
    if (tid == 0)
        partials[blockIdx.x] = ws[0] + ws[1] + ws[2] + ws[3];   // plain store, no init needed
}

__global__ __launch_bounds__(256)
void chamfer_final(const float* __restrict__ partials, float* __restrict__ out) {
    const int tid = threadIdx.x;
    float v = partials[tid];                 // NRED == 256 == blockDim
    #pragma unroll
    for (int off = 32; off; off >>= 1) v += __shfl_down(v, off, 64);
    __shared__ float ws[4];
    if ((tid & 63) == 0) ws[tid >> 6] = v;
    __syncthreads();
    if (tid == 0)
        out[0] = (ws[0] + ws[1] + ws[2] + ws[3]) * (1.0f / NPT_TOT);
}

extern "C" void kernel_launch(void* const* d_in, const int* in_sizes, int n_in,
                              void* d_out, int out_size, void* d_ws, size_t ws_size,
                              hipStream_t stream) {
    const float* p1 = (const float*)d_in[0];
    const float* p2 = (const float*)d_in[1];
    float* out = (float*)d_out;

    float* mintab   = (float*)d_ws;                                   // 4 MB
    float* partials = (float*)((char*)d_ws + (size_t)YSEG * NPT_TOT * 4);

    chamfer_fused<<<dim3(8, 8, YSEG), 256, 0, stream>>>(p1, p2, mintab);
    chamfer_reduce<<<dim3(NRED), 256, 0, stream>>>(mintab, partials);
    chamfer_final<<<1, 256, 0, stream>>>(partials, out);
}